// Round 9
// baseline (97.270 us; speedup 1.0000x reference)
//
#include <hip/hip_runtime.h>

namespace {

constexpr int T = 512;
constexpr int K = 4;
constexpr int G = 20000;
constexpr int EPG = 3;
constexpr int B = 512;
constexpr int BT = 2;                  // b's per slab
constexpr int NSLAB = B / BT;          // 256 (grid x, fast dim)
constexpr int NG = 6;                  // g-splits (grid y, slow dim)
constexpr int GPB = 3584;              // g's per block (14 chunks)
constexpr int NCHUNK = GPB / 256;      // 14
constexpr int GPAD = NG * GPB;         // 21504
constexpr int RS = 12;                 // LDS row stride in dwords (48 B):
                                       // 12t mod 32 tiles all 32 banks (8 classes)
constexpr float SLOPE = 0.01f;

__device__ __forceinline__ float lrelu(float x) { return fmaxf(x, SLOPE * x); }
__device__ __forceinline__ float dot4(float4 a, float4 b) {
  return a.x * b.x + a.y * b.y + a.z * b.z + a.w * b.w;
}

// Prep: dense SoA records. R0/R1/R2 = w3 edge rows; RM = (bias, off0..2) with
// off_e = t_e * 48 (byte offset of row t_e in the 24KB slab). Padded g's get
// zero weights + offset 0 (safe reads; stores guarded).
__global__ __launch_bounds__(256) void prep_kernel(
    const float* __restrict__ w3, const float* __restrict__ b3,
    const int* __restrict__ edge, float4* __restrict__ R0,
    float4* __restrict__ R1, float4* __restrict__ R2, float4* __restrict__ RM) {
  const int g = blockIdx.x * 256 + threadIdx.x;  // 0..GPAD-1
  float4 a = make_float4(0.f, 0.f, 0.f, 0.f), b = a, c = a, m = a;
  if (g < G) {
    const float4* wp = reinterpret_cast<const float4*>(w3 + (size_t)g * (EPG * K));
    a = wp[0];
    b = wp[1];
    c = wp[2];
    m.x = b3[g];
    m.y = __int_as_float(edge[g * EPG + 0] * (RS * 4));
    m.z = __int_as_float(edge[g * EPG + 1] * (RS * 4));
    m.w = __int_as_float(edge[g * EPG + 2] * (RS * 4));
  } else {
    m.y = m.z = m.w = __int_as_float(0);
  }
  R0[g] = a; R1[g] = b; R2[g] = c; RM[g] = m;
}

// Fused kernel, BT=2. 24KB LDS -> 6 blocks/CU (24 waves/CU); <=64 VGPR
// (launch_bounds min-8-waves) so occupancy is LDS-limited, not VGPR-limited.
// Grid (256 slabs x 6 g-splits) = 1536 blocks = exactly 6/CU, one balanced
// generation. Phase 2 chunk: 4 dense float4 record loads, 6 ds_read_b128,
// 24 FMA, 2 coalesced 256B store segments; TLP (24 waves) hides latency.
__global__ __launch_bounds__(256, 8) void fused_kernel(
    const float* __restrict__ features, const float* __restrict__ w1,
    const float* __restrict__ b1, const float* __restrict__ w2,
    const float* __restrict__ b2, const float4* __restrict__ R0,
    const float4* __restrict__ R1, const float4* __restrict__ R2,
    const float4* __restrict__ RM, float* __restrict__ out) {
  __shared__ float lds[T * RS];  // 24 KB
  const int tid = threadIdx.x;
  const int b0 = blockIdx.x * BT;
  const int gbase = blockIdx.y * GPB;

  // ---- Phase 1: h2 slab (2 b's) -> LDS ----
#pragma unroll
  for (int half = 0; half < 2; ++half) {
    const int t = half * 256 + tid;
    const float4 W1 = reinterpret_cast<const float4*>(w1)[t];
    const float4 B1 = reinterpret_cast<const float4*>(b1)[t];
    const float4 B2 = reinterpret_cast<const float4*>(b2)[t];
    const float4* W2 = reinterpret_cast<const float4*>(w2) + t * 4;
    const float4 r0 = W2[0];
    const float4 r1 = W2[1];
    const float4 r2 = W2[2];
    const float4 r3 = W2[3];
#pragma unroll
    for (int b = 0; b < BT; ++b) {
      const float f = features[(size_t)(b0 + b) * T + t];
      const float h0 = lrelu(f * W1.x + B1.x);
      const float h1 = lrelu(f * W1.y + B1.y);
      const float h2 = lrelu(f * W1.z + B1.z);
      const float h3 = lrelu(f * W1.w + B1.w);
      float4 o;
      o.x = lrelu(B2.x + h0 * r0.x + h1 * r1.x + h2 * r2.x + h3 * r3.x);
      o.y = lrelu(B2.y + h0 * r0.y + h1 * r1.y + h2 * r2.y + h3 * r3.y);
      o.z = lrelu(B2.z + h0 * r0.z + h1 * r1.z + h2 * r2.z + h3 * r3.z);
      o.w = lrelu(B2.w + h0 * r0.w + h1 * r1.w + h2 * r2.w + h3 * r3.w);
      *reinterpret_cast<float4*>(&lds[t * RS + b * 4]) = o;
    }
  }
  __syncthreads();  // the only barrier

  const char* ldsc = reinterpret_cast<const char*>(lds);

  // ---- Phase 2: barrier-free g-loop, minimal live registers ----
  for (int s = 0; s < NCHUNK; ++s) {
    const int g = gbase + s * 256 + tid;
    const float4 c0 = R0[g];
    const float4 c1 = R1[g];
    const float4 c2 = R2[g];
    const float4 cm = RM[g];
    const int o0 = __float_as_int(cm.y);
    const int o1 = __float_as_int(cm.z);
    const int o2 = __float_as_int(cm.w);
    float a0 = cm.x, a1 = cm.x;
    {
      const float4 v0 = *reinterpret_cast<const float4*>(ldsc + o0);
      const float4 v1 = *reinterpret_cast<const float4*>(ldsc + o0 + 16);
      a0 += dot4(v0, c0);
      a1 += dot4(v1, c0);
    }
    {
      const float4 v0 = *reinterpret_cast<const float4*>(ldsc + o1);
      const float4 v1 = *reinterpret_cast<const float4*>(ldsc + o1 + 16);
      a0 += dot4(v0, c1);
      a1 += dot4(v1, c1);
    }
    {
      const float4 v0 = *reinterpret_cast<const float4*>(ldsc + o2);
      const float4 v1 = *reinterpret_cast<const float4*>(ldsc + o2 + 16);
      a0 += dot4(v0, c2);
      a1 += dot4(v1, c2);
    }
    if (g < G) {
      __builtin_nontemporal_store(a0, &out[(size_t)(b0 + 0) * G + g]);
      __builtin_nontemporal_store(a1, &out[(size_t)(b0 + 1) * G + g]);
    }
  }
}

}  // namespace

extern "C" void kernel_launch(void* const* d_in, const int* in_sizes, int n_in,
                              void* d_out, int out_size, void* d_ws, size_t ws_size,
                              hipStream_t stream) {
  const float* features = (const float*)d_in[0];
  const float* w1 = (const float*)d_in[1];
  const float* b1 = (const float*)d_in[2];
  const float* w2 = (const float*)d_in[3];
  const float* b2 = (const float*)d_in[4];
  const float* w3 = (const float*)d_in[5];
  const float* b3 = (const float*)d_in[6];
  const int* edge = (const int*)d_in[7];
  float* out = (float*)d_out;

  float4* R0 = (float4*)d_ws;  // 4 dense SoA arrays, 336 KB each
  float4* R1 = R0 + GPAD;
  float4* R2 = R1 + GPAD;
  float4* RM = R2 + GPAD;

  prep_kernel<<<GPAD / 256, 256, 0, stream>>>(w3, b3, edge, R0, R1, R2, RM);

  dim3 grid(NSLAB, NG);  // (256, 6): 1536 blocks = 6/CU, one generation
  fused_kernel<<<grid, 256, 0, stream>>>(features, w1, b1, w2, b2, R0, R1, R2,
                                         RM, out);
}